// Round 3
// baseline (256.190 us; speedup 1.0000x reference)
//
#include <hip/hip_runtime.h>
#include <stdint.h>

// ODE sampler (VP-SDE probability-flow, RK4, T=50) for B=2048, D=16, H=256.
// tr(J) analytic: tr = -0.5*beta*(D + sum_k (1-h_k^2)*c_k).
//
// R9: TLP split. R6-R8 evidence: wall = 1530cy/Feval/SIMD vs ~500cy issue
// -> structurally stall-bound at 2 waves/SIMD (grid 2048 waves pins it).
// Split each sample across 2 waves (block=128):
//  - phase 1 (256 hidden units) split: 2 h per lane (16 fdot2 + 2 tanh,
//    was 32 + 4); h written to LDS as one b32 per lane (same chunk layout).
//  - phase 2 + bcast + RK update DUPLICATED per wave (identical results) --
//    no cross-wave eval-point exchange, ONE __syncthreads per Feval.
//  - h double-buffered; race-free with a single barrier: phase1(n+2)'s
//    write to buf[n&1] is ordered after barrier(n+1) which is after every
//    wave's phase2(n) reads of buf[n&1].
//  - waves/SIMD 2 -> 4; per-wave issue ~110 -> ~90 instr/Feval.
// Carried from R8: pkz packs, hoisted uniforms, b2/8 + WBSUM/cksum folds,
// SGPR x-broadcast via readlane, DPP-only reduce, CH=20 h layout, exp2 tanh.

typedef _Float16 f16x2 __attribute__((ext_vector_type(2)));

#if defined(__has_builtin)
#if __has_builtin(__builtin_amdgcn_fdot2)
#define HAVE_FDOT2 1
#endif
#endif

__device__ __forceinline__ float fdot2f(f16x2 a, f16x2 b, float c) {
#ifdef HAVE_FDOT2
    return __builtin_amdgcn_fdot2(a, b, c, false);
#else
    return fmaf((float)a.y, (float)b.y, fmaf((float)a.x, (float)b.x, c));
#endif
}

// hot path: single-instruction pack (v_cvt_pkrtz_f16_f32)
__device__ __forceinline__ uint32_t pkz(float a, float b) {
    auto v = __builtin_amdgcn_cvt_pkrtz(a, b);
    return __builtin_bit_cast(uint32_t, v);
}
__device__ __forceinline__ f16x2 upk(uint32_t u) {
    return __builtin_bit_cast(f16x2, u);
}

// DPP add: x + x_from(lane permuted by ctrl); VALU pipe, no DS.
#define DPP_XOR1 0xB1    // quad_perm [1,0,3,2]
#define DPP_XOR2 0x4E    // quad_perm [2,3,0,1]
#define DPP_RHM  0x141   // row_half_mirror (xor-7 within 8-lane half-row)
template <int CTRL>
__device__ __forceinline__ float dpp_add(float x) {
    int v = __builtin_amdgcn_update_dpp(
        0, __builtin_bit_cast(int, x), CTRL, 0xF, 0xF, true);
    return x + __builtin_bit_cast(float, v);
}

#define Bn 2048
#define Dn 16
#define Hn 256
#define Tn 50
#define CH 20            // dwords per 32-k h chunk: 16 data + 4 pad

constexpr float T_LO = 1e-3f;
constexpr float DTc  = (1.0f - 1e-3f) / (float)(Tn - 1);
constexpr float W1W  = DTc * (1.f / 6.f);
constexpr float W2W  = DTc * (2.f / 6.f);

constexpr float nh_c(float t) { return -0.5f * (0.1f + 19.9f * t); }
constexpr float wbsum_c() {
    float s = 0.f;
    for (int j = 0; j < Tn - 1; ++j) {
        float t0 = T_LO + (float)j * DTc;
        float tm = t0 + 0.5f * DTc;
        float t1 = t0 + DTc;
        s += W1W * nh_c(t0) + 2.f * W2W * nh_c(tm) + W1W * nh_c(t1);
    }
    return s;
}
constexpr float WBSUM = wbsum_c();   // sum of RK-weighted (-beta/2) factors

__global__ __launch_bounds__(128) void ode_kernel(
    const float* __restrict__ x_in,   // [B][D]
    const float* __restrict__ W1,     // [D][H]
    const float* __restrict__ b1v,    // [H]
    const float* __restrict__ wtv,    // [H]
    const float* __restrict__ W2,     // [H][D]
    const float* __restrict__ b2v,    // [D]
    float* __restrict__ out)          // xf[B*D] | ldjf[B] | xt[T*B*D]
{
    __shared__ __align__(16) uint32_t h_lds[2][8 * CH];  // h dbuf, f16-packed
    __shared__ float ldj_x[2];

    const int tid = threadIdx.x;      // 0..127: two waves per sample
    const int L   = tid & 63;
    const int g8  = L >> 3;           // i-pair group 0..7 (phase 2)
    const int c   = L & 7;            // phase-2 k-chunk (32 k's)
    const int ia = 2 * g8, ib = ia + 1;
    const int gs = blockIdx.x;

    const float K2 = 2.88539008f;     // 2*log2(e): u' = K2*u, exp2(u') = e^{2u}

    // ---- one-time init: phase-1 owns k in {2*tid, 2*tid+1} ----
    f16x2 w1p[2][8];                  // prescaled: {K2*W1[2j][k], K2*W1[2j+1][k]}
    float b1k[2], wtk[2], ck[2];
    #pragma unroll
    for (int q = 0; q < 2; ++q) {
        const int k = 2 * tid + q;
        #pragma unroll
        for (int j = 0; j < 8; ++j) {
            f16x2 v;
            v.x = (_Float16)(K2 * W1[(2 * j)     * Hn + k]);
            v.y = (_Float16)(K2 * W1[(2 * j + 1) * Hn + k]);
            w1p[q][j] = v;
        }
        b1k[q] = K2 * b1v[k];
        wtk[q] = K2 * wtv[k];
        float s = 0.f;                // ck from ORIGINAL f32 weights
        #pragma unroll
        for (int ii = 0; ii < 16; ++ii)
            s = fmaf(W1[ii * Hn + k], W2[k * Dn + ii], s);
        ck[q] = s;
    }
    const float cks = ck[0] + ck[1];

    f16x2 w2a[16], w2b[16];           // duplicated per wave (phase 2 is dup'd)
    #pragma unroll
    for (int m = 0; m < 16; ++m) {
        f16x2 va, vb;
        va.x = (_Float16)W2[(32 * c + 2 * m)     * Dn + ia];
        va.y = (_Float16)W2[(32 * c + 2 * m + 1) * Dn + ia];
        vb.x = (_Float16)W2[(32 * c + 2 * m)     * Dn + ib];
        vb.y = (_Float16)W2[(32 * c + 2 * m + 1) * Dn + ib];
        w2a[m] = va; w2b[m] = vb;
    }
    const float b2a8 = 0.125f * b2v[ia];   // b2 / 8: folded into accumulator
    const float b2b8 = 0.125f * b2v[ib];   // init, restored by the 8-lane sum

    float xa = x_in[gs * Dn + ia];
    float xb = x_in[gs * Dn + ib];
    float ldjl = 0.f;                 // per-lane ldj partial (its 2 k's)

    float* xf_out  = out;
    float* ldj_out = out + (size_t)Bn * Dn;
    float* xt_ptr  = out + (size_t)Bn * Dn + Bn + gs * Dn + ia;

    // store mask: wave 0 AND c == 0  <=>  (tid & 0x47) == 0
    if ((tid & 0x47) == 0) *(float2*)xt_ptr = make_float2(xa, xb);   // xt[0]
    xt_ptr += Bn * Dn;

    const int hw = CH * (tid >> 4) + (tid & 15);   // h write slot (b32)

    // eval-point broadcast registers (uniform per wave -> SGPRs)
    uint32_t se0, se1, se2, se3, se4, se5, se6, se7;
    auto bcast = [&](float ea, float eb) {
        const uint32_t vpk = pkz(ea, eb);     // every lane packs ITS pair
        se0 = __builtin_amdgcn_readlane(vpk,  0);
        se1 = __builtin_amdgcn_readlane(vpk,  8);
        se2 = __builtin_amdgcn_readlane(vpk, 16);
        se3 = __builtin_amdgcn_readlane(vpk, 24);
        se4 = __builtin_amdgcn_readlane(vpk, 32);
        se5 = __builtin_amdgcn_readlane(vpk, 40);
        se6 = __builtin_amdgcn_readlane(vpk, 48);
        se7 = __builtin_amdgcn_readlane(vpk, 56);
    };

    int fe = 0;                       // Feval counter -> h buffer parity

    auto Feval = [&](float xeva, float xevb, const float (&ui)[2],
                     float nhb, float wb, float& dxa, float& dxb) {
        uint32_t* hb = h_lds[fe & 1]; ++fe;

        // ---- phase 1 (split): this lane's 2 hidden units ----
        const f16x2 xp[8] = { upk(se0), upk(se1), upk(se2), upk(se3),
                              upk(se4), upk(se5), upk(se6), upk(se7) };
        float u0 = ui[0], u1 = ui[1];
        #pragma unroll
        for (int j = 0; j < 8; ++j) {
            u0 = fdot2f(xp[j], w1p[0][j], u0);
            u1 = fdot2f(xp[j], w1p[1][j], u1);
        }
        // u is prescaled: exp2(u) = e^{2u_true}. tanh = 1 - 2/(E+1).
        const float h0 = fmaf(-2.f, __builtin_amdgcn_rcpf(__builtin_amdgcn_exp2f(u0) + 1.f), 1.f);
        const float h1 = fmaf(-2.f, __builtin_amdgcn_rcpf(__builtin_amdgcn_exp2f(u1) + 1.f), 1.f);
        hb[hw] = pkz(h0, h1);

        // trace partial: ldjl -= wb * (h0^2*ck0 + h1^2*ck1)
        const float q0 = h0 * h0, q1 = h1 * h1;
        const float sq = fmaf(q0, ck[0], q1 * ck[1]);
        ldjl = fmaf(-wb, sq, ldjl);

        __syncthreads();              // h (both waves) visible to phase 2

        // ---- phase 2 (duplicated per wave): score for (ia, ib), chunk c ----
        float sa0 = b2a8, sa1 = 0.f, sb0 = b2b8, sb1 = 0.f;
        #pragma unroll
        for (int mq = 0; mq < 4; ++mq) {
            const uint4 hv = *(const uint4*)&hb[CH * c + 4 * mq];
            const f16x2 p0 = upk(hv.x), p1 = upk(hv.y), p2 = upk(hv.z), p3 = upk(hv.w);
            sa0 = fdot2f(p0, w2a[4 * mq + 0], sa0);
            sb0 = fdot2f(p0, w2b[4 * mq + 0], sb0);
            sa1 = fdot2f(p1, w2a[4 * mq + 1], sa1);
            sb1 = fdot2f(p1, w2b[4 * mq + 1], sb1);
            sa0 = fdot2f(p2, w2a[4 * mq + 2], sa0);
            sb0 = fdot2f(p2, w2b[4 * mq + 2], sb0);
            sa1 = fdot2f(p3, w2a[4 * mq + 3], sa1);
            sb1 = fdot2f(p3, w2b[4 * mq + 3], sb1);
        }
        float sca = sa0 + sa1, scb = sb0 + sb1;
        // 8-lane reduce on the VALU pipe (DPP), no DS ops:
        sca = dpp_add<DPP_XOR1>(sca);  scb = dpp_add<DPP_XOR1>(scb);
        sca = dpp_add<DPP_XOR2>(sca);  scb = dpp_add<DPP_XOR2>(scb);
        sca = dpp_add<DPP_RHM >(sca);  scb = dpp_add<DPP_RHM >(scb);

        dxa = nhb * (xeva + sca);
        dxb = nhb * (xevb + scb);
    };

    // per-t-value uniforms, hoisted off the Feval critical path
    float ui0[2], uim[2], uit[2];
    #pragma unroll
    for (int q = 0; q < 2; ++q) ui0[q] = fmaf(T_LO, wtk[q], b1k[q]);
    float nhb0 = -0.5f * fmaf(T_LO, 19.9f, 0.1f);

    bcast(xa, xb);
    for (int j = 0; j < Tn - 1; ++j) {
        const float t0 = fmaf((float)j, DTc, T_LO);
        const float tm = t0 + 0.5f * DTc;
        const float t1 = t0 + DTc;
        #pragma unroll
        for (int q = 0; q < 2; ++q) {
            uim[q] = fmaf(tm, wtk[q], b1k[q]);
            uit[q] = fmaf(t1, wtk[q], b1k[q]);
        }
        const float nhbm = -0.5f * fmaf(tm, 19.9f, 0.1f);
        const float nhb1 = -0.5f * fmaf(t1, 19.9f, 0.1f);
        const float wb0 = W1W * nhb0;
        const float wbm = W2W * nhbm;      // shared by k2 and k3
        const float wb1 = W1W * nhb1;

        float k1a, k1b, k2a, k2b, k3a, k3b, k4a, k4b;

        Feval(xa, xb, ui0, nhb0, wb0, k1a, k1b);
        const float e2a = fmaf(0.5f * DTc, k1a, xa);
        const float e2b = fmaf(0.5f * DTc, k1b, xb);
        bcast(e2a, e2b);
        Feval(e2a, e2b, uim, nhbm, wbm, k2a, k2b);
        const float e3a = fmaf(0.5f * DTc, k2a, xa);
        const float e3b = fmaf(0.5f * DTc, k2b, xb);
        bcast(e3a, e3b);
        Feval(e3a, e3b, uim, nhbm, wbm, k3a, k3b);
        const float e4a = fmaf(DTc, k3a, xa);
        const float e4b = fmaf(DTc, k3b, xb);
        bcast(e4a, e4b);
        Feval(e4a, e4b, uit, nhb1, wb1, k4a, k4b);

        xa = fmaf(W1W, k1a + 2.f * (k2a + k3a) + k4a, xa);
        xb = fmaf(W1W, k1b + 2.f * (k2b + k3b) + k4b, xb);
        if ((tid & 0x47) == 0) *(float2*)xt_ptr = make_float2(xa, xb);
        xt_ptr += Bn * Dn;
        bcast(xa, xb);

        #pragma unroll
        for (int q = 0; q < 2; ++q) ui0[q] = uit[q];   // t1 -> next t0
        nhb0 = nhb1;
    }

    if ((tid & 0x47) == 0) *(float2*)(xf_out + gs * Dn + ia) = make_float2(xa, xb);

    // ldj: fold constant (D/128 + ck0 + ck1) * WBSUM per lane, butterfly
    // within each wave, then combine the two wave partials via LDS.
    ldjl = fmaf(cks + 0.125f, WBSUM, ldjl);
    #pragma unroll
    for (int off = 1; off < 64; off <<= 1)
        ldjl += __shfl_xor(ldjl, off);
    if (L == 0) ldj_x[tid >> 6] = ldjl;
    __syncthreads();
    if (tid == 0) ldj_out[gs] = ldj_x[0] + ldj_x[1];
}

extern "C" void kernel_launch(void* const* d_in, const int* in_sizes, int n_in,
                              void* d_out, int out_size, void* d_ws, size_t ws_size,
                              hipStream_t stream) {
    const float* x  = (const float*)d_in[0];
    const float* W1 = (const float*)d_in[1];
    const float* b1 = (const float*)d_in[2];
    const float* wt = (const float*)d_in[3];
    const float* W2 = (const float*)d_in[4];
    const float* b2 = (const float*)d_in[5];
    (void)in_sizes; (void)n_in; (void)out_size; (void)d_ws; (void)ws_size;
    ode_kernel<<<Bn, 128, 0, stream>>>(x, W1, b1, wt, W2, b2, (float*)d_out);
}

// Round 4
// 173.532 us; speedup vs baseline: 1.4763x; 1.4763x over previous
//
#include <hip/hip_runtime.h>
#include <stdint.h>

// ODE sampler (VP-SDE probability-flow, RK4, T=50) for B=2048, D=16, H=256.
// tr(J) analytic: tr = -0.5*beta*(D + sum_k (1-h_k^2)*c_k).
//
// R10: two samples per wave, zero barriers. Evidence: R8 wall = 1500
// cy/Feval/SIMD vs ~430-800 cy issue (stall-bound, HW wave-interleave not
// filling holes); R9's barrier-based wave split regressed 77% (200
// syncthreads, each a vmcnt+lgkmcnt drain + lockstep skew).
// Grid 1024 x 64: each wave integrates samples 2gs and 2gs+1.
//  - Weights w1p/w2a/w2b/ck and time-uniforms ui/nhb/wb are SHARED; only
//    x-state, h, accumulators, ldj duplicate (VGPR ~180, fine at 1
//    wave/SIMD where the budget is 512).
//  - The two independent per-sample chains give the compiler 2x ILP:
//    s1's phase-1 fills s0's DS write->read bubble, s0's exp2/rcp latency
//    hides under s1's dot chains. No __syncthreads anywhere.
//  - Per-SIMD issue per Feval unchanged vs R8 (1 wave x 2 samples vs
//    2 waves x 1 sample) -- this isolates scheduling, not work.
// Carried from R8: pkz packs, hoisted uniforms, b2/8 + WBSUM/cksum folds,
// SGPR x-broadcast via readlane, DPP-only reduce, CH=20 h layout, exp2 tanh.

typedef _Float16 f16x2 __attribute__((ext_vector_type(2)));

#if defined(__has_builtin)
#if __has_builtin(__builtin_amdgcn_fdot2)
#define HAVE_FDOT2 1
#endif
#endif

__device__ __forceinline__ float fdot2f(f16x2 a, f16x2 b, float c) {
#ifdef HAVE_FDOT2
    return __builtin_amdgcn_fdot2(a, b, c, false);
#else
    return fmaf((float)a.y, (float)b.y, fmaf((float)a.x, (float)b.x, c));
#endif
}

// hot path: single-instruction pack (v_cvt_pkrtz_f16_f32)
__device__ __forceinline__ uint32_t pkz(float a, float b) {
    auto v = __builtin_amdgcn_cvt_pkrtz(a, b);
    return __builtin_bit_cast(uint32_t, v);
}
__device__ __forceinline__ f16x2 upk(uint32_t u) {
    return __builtin_bit_cast(f16x2, u);
}

// DPP add: x + x_from(lane permuted by ctrl); VALU pipe, no DS.
#define DPP_XOR1 0xB1    // quad_perm [1,0,3,2]
#define DPP_XOR2 0x4E    // quad_perm [2,3,0,1]
#define DPP_RHM  0x141   // row_half_mirror (xor-7 within 8-lane half-row)
template <int CTRL>
__device__ __forceinline__ float dpp_add(float x) {
    int v = __builtin_amdgcn_update_dpp(
        0, __builtin_bit_cast(int, x), CTRL, 0xF, 0xF, true);
    return x + __builtin_bit_cast(float, v);
}

#define Bn 2048
#define Dn 16
#define Hn 256
#define Tn 50
#define CH 20            // dwords per 32-k h chunk: 16 data + 4 pad

constexpr float T_LO = 1e-3f;
constexpr float DTc  = (1.0f - 1e-3f) / (float)(Tn - 1);
constexpr float W1W  = DTc * (1.f / 6.f);
constexpr float W2W  = DTc * (2.f / 6.f);

constexpr float nh_c(float t) { return -0.5f * (0.1f + 19.9f * t); }
constexpr float wbsum_c() {
    float s = 0.f;
    for (int j = 0; j < Tn - 1; ++j) {
        float t0 = T_LO + (float)j * DTc;
        float tm = t0 + 0.5f * DTc;
        float t1 = t0 + DTc;
        s += W1W * nh_c(t0) + 2.f * W2W * nh_c(tm) + W1W * nh_c(t1);
    }
    return s;
}
constexpr float WBSUM = wbsum_c();   // sum of RK-weighted (-beta/2) factors

__global__ __launch_bounds__(64) void ode_kernel(
    const float* __restrict__ x_in,   // [B][D]
    const float* __restrict__ W1,     // [D][H]
    const float* __restrict__ b1v,    // [H]
    const float* __restrict__ wtv,    // [H]
    const float* __restrict__ W2,     // [H][D]
    const float* __restrict__ b2v,    // [D]
    float* __restrict__ out)          // xf[B*D] | ldjf[B] | xt[T*B*D]
{
    __shared__ __align__(16) uint32_t h_lds[2][8 * CH];  // h per sample

    const int L  = threadIdx.x;       // one wave = two samples
    const int g8 = L >> 3;            // i-pair group 0..7
    const int c  = L & 7;             // phase-2 k-chunk (32 k's)
    const int ia = 2 * g8, ib = ia + 1;
    const int k0 = 4 * L;             // phase-1: this lane's 4 hidden units
    const int gs0 = 2 * blockIdx.x, gs1 = gs0 + 1;

    const float K2 = 2.88539008f;     // 2*log2(e): u' = K2*u, exp2(u') = e^{2u}

    // ---- one-time init: weights packed to f16 registers (SHARED) ----
    f16x2 w1p[4][8];                  // prescaled: {K2*W1[2j][k0+q], K2*W1[2j+1][k0+q]}
    float b1k[4], wtk[4], ck[4];
    #pragma unroll
    for (int q = 0; q < 4; ++q) {
        const int k = k0 + q;
        #pragma unroll
        for (int j = 0; j < 8; ++j) {
            f16x2 v;
            v.x = (_Float16)(K2 * W1[(2 * j)     * Hn + k]);
            v.y = (_Float16)(K2 * W1[(2 * j + 1) * Hn + k]);
            w1p[q][j] = v;
        }
        b1k[q] = K2 * b1v[k];
        wtk[q] = K2 * wtv[k];
        float s = 0.f;                // ck from ORIGINAL f32 weights
        #pragma unroll
        for (int ii = 0; ii < 16; ++ii)
            s = fmaf(W1[ii * Hn + k], W2[k * Dn + ii], s);
        ck[q] = s;
    }
    const float cksum = (ck[0] + ck[1]) + (ck[2] + ck[3]);

    f16x2 w2a[16], w2b[16];           // [m] = {W2[32c+2m][i*], W2[32c+2m+1][i*]}
    #pragma unroll
    for (int m = 0; m < 16; ++m) {
        f16x2 va, vb;
        va.x = (_Float16)W2[(32 * c + 2 * m)     * Dn + ia];
        va.y = (_Float16)W2[(32 * c + 2 * m + 1) * Dn + ia];
        vb.x = (_Float16)W2[(32 * c + 2 * m)     * Dn + ib];
        vb.y = (_Float16)W2[(32 * c + 2 * m + 1) * Dn + ib];
        w2a[m] = va; w2b[m] = vb;
    }
    const float b2a8 = 0.125f * b2v[ia];   // b2 / 8: folded into accumulator
    const float b2b8 = 0.125f * b2v[ib];   // init, restored by the 8-lane sum

    float xa0 = x_in[gs0 * Dn + ia], xb0 = x_in[gs0 * Dn + ib];
    float xa1 = x_in[gs1 * Dn + ia], xb1 = x_in[gs1 * Dn + ib];
    float ldj0 = 0.f, ldj1 = 0.f;     // per-lane ldj partials

    float* xf_out  = out;
    float* ldj_out = out + (size_t)Bn * Dn;
    float* xt_ptr  = out + (size_t)Bn * Dn + Bn + gs0 * Dn + ia;  // s1 = +Dn

    if (c == 0) {
        *(float2*)xt_ptr        = make_float2(xa0, xb0);   // xt[0], s0
        *(float2*)(xt_ptr + Dn) = make_float2(xa1, xb1);   // xt[0], s1
    }
    xt_ptr += Bn * Dn;

    const int hwidx = CH * (L >> 3) + 2 * (L & 7);        // h write slot (b64)

    // eval-point broadcast registers (uniform -> SGPRs), one set per sample
    uint32_t se[8], te[8];
    auto bcast = [&](float ea, float eb, uint32_t (&sg)[8]) {
        const uint32_t vpk = pkz(ea, eb);     // every lane packs ITS pair
        sg[0] = __builtin_amdgcn_readlane(vpk,  0);
        sg[1] = __builtin_amdgcn_readlane(vpk,  8);
        sg[2] = __builtin_amdgcn_readlane(vpk, 16);
        sg[3] = __builtin_amdgcn_readlane(vpk, 24);
        sg[4] = __builtin_amdgcn_readlane(vpk, 32);
        sg[5] = __builtin_amdgcn_readlane(vpk, 40);
        sg[6] = __builtin_amdgcn_readlane(vpk, 48);
        sg[7] = __builtin_amdgcn_readlane(vpk, 56);
    };

    auto Feval = [&](float xva0, float xvb0, float xva1, float xvb1,
                     const float (&ui)[4], float nhb, float wb,
                     float& dxa0, float& dxb0, float& dxa1, float& dxb1) {
        // ---- phase 1, both samples: 8 independent dot chains ----
        float u00 = ui[0], u01 = ui[1], u02 = ui[2], u03 = ui[3];
        float u10 = ui[0], u11 = ui[1], u12 = ui[2], u13 = ui[3];
        #pragma unroll
        for (int j = 0; j < 8; ++j) {
            const f16x2 xp0 = upk(se[j]);
            const f16x2 xp1 = upk(te[j]);
            u00 = fdot2f(xp0, w1p[0][j], u00);
            u10 = fdot2f(xp1, w1p[0][j], u10);
            u01 = fdot2f(xp0, w1p[1][j], u01);
            u11 = fdot2f(xp1, w1p[1][j], u11);
            u02 = fdot2f(xp0, w1p[2][j], u02);
            u12 = fdot2f(xp1, w1p[2][j], u12);
            u03 = fdot2f(xp0, w1p[3][j], u03);
            u13 = fdot2f(xp1, w1p[3][j], u13);
        }
        // u is prescaled: exp2(u) = e^{2u_true}. tanh = 1 - 2/(E+1).
        const float h00 = fmaf(-2.f, __builtin_amdgcn_rcpf(__builtin_amdgcn_exp2f(u00) + 1.f), 1.f);
        const float h01 = fmaf(-2.f, __builtin_amdgcn_rcpf(__builtin_amdgcn_exp2f(u01) + 1.f), 1.f);
        const float h02 = fmaf(-2.f, __builtin_amdgcn_rcpf(__builtin_amdgcn_exp2f(u02) + 1.f), 1.f);
        const float h03 = fmaf(-2.f, __builtin_amdgcn_rcpf(__builtin_amdgcn_exp2f(u03) + 1.f), 1.f);
        const float h10 = fmaf(-2.f, __builtin_amdgcn_rcpf(__builtin_amdgcn_exp2f(u10) + 1.f), 1.f);
        const float h11 = fmaf(-2.f, __builtin_amdgcn_rcpf(__builtin_amdgcn_exp2f(u11) + 1.f), 1.f);
        const float h12 = fmaf(-2.f, __builtin_amdgcn_rcpf(__builtin_amdgcn_exp2f(u12) + 1.f), 1.f);
        const float h13 = fmaf(-2.f, __builtin_amdgcn_rcpf(__builtin_amdgcn_exp2f(u13) + 1.f), 1.f);
        *(uint2*)&h_lds[0][hwidx] = make_uint2(pkz(h00, h01), pkz(h02, h03));
        *(uint2*)&h_lds[1][hwidx] = make_uint2(pkz(h10, h11), pkz(h12, h13));

        // trace partials (independent work inside the DS write->read bubble)
        const float sq0 = fmaf(h00 * h00, ck[0], fmaf(h01 * h01, ck[1],
                          fmaf(h02 * h02, ck[2], (h03 * h03) * ck[3])));
        const float sq1 = fmaf(h10 * h10, ck[0], fmaf(h11 * h11, ck[1],
                          fmaf(h12 * h12, ck[2], (h13 * h13) * ck[3])));
        ldj0 = fmaf(-wb, sq0, ldj0);
        ldj1 = fmaf(-wb, sq1, ldj1);

        asm volatile("" ::: "memory");     // keep h writes above the reads

        // ---- phase 2, both samples: score over k-chunk c ----
        float sa0 = b2a8, sa1 = 0.f, sb0 = b2b8, sb1 = 0.f;   // sample 0
        float ra0 = b2a8, ra1 = 0.f, rb0 = b2b8, rb1 = 0.f;   // sample 1
        #pragma unroll
        for (int mq = 0; mq < 4; ++mq) {
            const uint4 hv0 = *(const uint4*)&h_lds[0][CH * c + 4 * mq];
            const uint4 hv1 = *(const uint4*)&h_lds[1][CH * c + 4 * mq];
            const f16x2 p00 = upk(hv0.x), p01 = upk(hv0.y), p02 = upk(hv0.z), p03 = upk(hv0.w);
            const f16x2 p10 = upk(hv1.x), p11 = upk(hv1.y), p12 = upk(hv1.z), p13 = upk(hv1.w);
            sa0 = fdot2f(p00, w2a[4 * mq + 0], sa0);
            ra0 = fdot2f(p10, w2a[4 * mq + 0], ra0);
            sb0 = fdot2f(p00, w2b[4 * mq + 0], sb0);
            rb0 = fdot2f(p10, w2b[4 * mq + 0], rb0);
            sa1 = fdot2f(p01, w2a[4 * mq + 1], sa1);
            ra1 = fdot2f(p11, w2a[4 * mq + 1], ra1);
            sb1 = fdot2f(p01, w2b[4 * mq + 1], sb1);
            rb1 = fdot2f(p11, w2b[4 * mq + 1], rb1);
            sa0 = fdot2f(p02, w2a[4 * mq + 2], sa0);
            ra0 = fdot2f(p12, w2a[4 * mq + 2], ra0);
            sb0 = fdot2f(p02, w2b[4 * mq + 2], sb0);
            rb0 = fdot2f(p12, w2b[4 * mq + 2], rb0);
            sa1 = fdot2f(p03, w2a[4 * mq + 3], sa1);
            ra1 = fdot2f(p13, w2a[4 * mq + 3], ra1);
            sb1 = fdot2f(p03, w2b[4 * mq + 3], sb1);
            rb1 = fdot2f(p13, w2b[4 * mq + 3], rb1);
        }
        float sca0 = sa0 + sa1, scb0 = sb0 + sb1;
        float sca1 = ra0 + ra1, scb1 = rb0 + rb1;
        // 8-lane reduce on the VALU pipe (DPP), no DS ops:
        sca0 = dpp_add<DPP_XOR1>(sca0);  scb0 = dpp_add<DPP_XOR1>(scb0);
        sca1 = dpp_add<DPP_XOR1>(sca1);  scb1 = dpp_add<DPP_XOR1>(scb1);
        sca0 = dpp_add<DPP_XOR2>(sca0);  scb0 = dpp_add<DPP_XOR2>(scb0);
        sca1 = dpp_add<DPP_XOR2>(sca1);  scb1 = dpp_add<DPP_XOR2>(scb1);
        sca0 = dpp_add<DPP_RHM >(sca0);  scb0 = dpp_add<DPP_RHM >(scb0);
        sca1 = dpp_add<DPP_RHM >(sca1);  scb1 = dpp_add<DPP_RHM >(scb1);

        dxa0 = nhb * (xva0 + sca0);
        dxb0 = nhb * (xvb0 + scb0);
        dxa1 = nhb * (xva1 + sca1);
        dxb1 = nhb * (xvb1 + scb1);
    };

    // per-t-value uniforms, hoisted off the Feval critical path (SHARED)
    float ui0[4], uim[4], uit[4];
    #pragma unroll
    for (int q = 0; q < 4; ++q) ui0[q] = fmaf(T_LO, wtk[q], b1k[q]);
    float nhb0 = -0.5f * fmaf(T_LO, 19.9f, 0.1f);

    bcast(xa0, xb0, se);
    bcast(xa1, xb1, te);
    for (int j = 0; j < Tn - 1; ++j) {
        const float t0 = fmaf((float)j, DTc, T_LO);
        const float tm = t0 + 0.5f * DTc;
        const float t1 = t0 + DTc;
        #pragma unroll
        for (int q = 0; q < 4; ++q) {
            uim[q] = fmaf(tm, wtk[q], b1k[q]);
            uit[q] = fmaf(t1, wtk[q], b1k[q]);
        }
        const float nhbm = -0.5f * fmaf(tm, 19.9f, 0.1f);
        const float nhb1 = -0.5f * fmaf(t1, 19.9f, 0.1f);
        const float wb0 = W1W * nhb0;
        const float wbm = W2W * nhbm;      // shared by k2 and k3
        const float wb1 = W1W * nhb1;

        float k1a0, k1b0, k2a0, k2b0, k3a0, k3b0, k4a0, k4b0;
        float k1a1, k1b1, k2a1, k2b1, k3a1, k3b1, k4a1, k4b1;

        Feval(xa0, xb0, xa1, xb1, ui0, nhb0, wb0, k1a0, k1b0, k1a1, k1b1);
        const float e2a0 = fmaf(0.5f * DTc, k1a0, xa0);
        const float e2b0 = fmaf(0.5f * DTc, k1b0, xb0);
        const float e2a1 = fmaf(0.5f * DTc, k1a1, xa1);
        const float e2b1 = fmaf(0.5f * DTc, k1b1, xb1);
        bcast(e2a0, e2b0, se);
        bcast(e2a1, e2b1, te);
        Feval(e2a0, e2b0, e2a1, e2b1, uim, nhbm, wbm, k2a0, k2b0, k2a1, k2b1);
        const float e3a0 = fmaf(0.5f * DTc, k2a0, xa0);
        const float e3b0 = fmaf(0.5f * DTc, k2b0, xb0);
        const float e3a1 = fmaf(0.5f * DTc, k2a1, xa1);
        const float e3b1 = fmaf(0.5f * DTc, k2b1, xb1);
        bcast(e3a0, e3b0, se);
        bcast(e3a1, e3b1, te);
        Feval(e3a0, e3b0, e3a1, e3b1, uim, nhbm, wbm, k3a0, k3b0, k3a1, k3b1);
        const float e4a0 = fmaf(DTc, k3a0, xa0);
        const float e4b0 = fmaf(DTc, k3b0, xb0);
        const float e4a1 = fmaf(DTc, k3a1, xa1);
        const float e4b1 = fmaf(DTc, k3b1, xb1);
        bcast(e4a0, e4b0, se);
        bcast(e4a1, e4b1, te);
        Feval(e4a0, e4b0, e4a1, e4b1, uit, nhb1, wb1, k4a0, k4b0, k4a1, k4b1);

        xa0 = fmaf(W1W, k1a0 + 2.f * (k2a0 + k3a0) + k4a0, xa0);
        xb0 = fmaf(W1W, k1b0 + 2.f * (k2b0 + k3b0) + k4b0, xb0);
        xa1 = fmaf(W1W, k1a1 + 2.f * (k2a1 + k3a1) + k4a1, xa1);
        xb1 = fmaf(W1W, k1b1 + 2.f * (k2b1 + k3b1) + k4b1, xb1);
        if (c == 0) {
            *(float2*)xt_ptr        = make_float2(xa0, xb0);
            *(float2*)(xt_ptr + Dn) = make_float2(xa1, xb1);
        }
        xt_ptr += Bn * Dn;
        bcast(xa0, xb0, se);
        bcast(xa1, xb1, te);

        #pragma unroll
        for (int q = 0; q < 4; ++q) ui0[q] = uit[q];   // t1 -> next t0
        nhb0 = nhb1;
    }

    if (c == 0) {
        *(float2*)(xf_out + gs0 * Dn + ia) = make_float2(xa0, xb0);
        *(float2*)(xf_out + gs1 * Dn + ia) = make_float2(xa1, xb1);
    }

    // ldj: fold the constant (D/64 + sum ck) * sum(wb) term, then butterfly
    ldj0 = fmaf(cksum + 0.25f, WBSUM, ldj0);
    ldj1 = fmaf(cksum + 0.25f, WBSUM, ldj1);
    #pragma unroll
    for (int off = 1; off < 64; off <<= 1) {
        ldj0 += __shfl_xor(ldj0, off);
        ldj1 += __shfl_xor(ldj1, off);
    }
    if (L == 0) {
        ldj_out[gs0] = ldj0;
        ldj_out[gs1] = ldj1;
    }
}

extern "C" void kernel_launch(void* const* d_in, const int* in_sizes, int n_in,
                              void* d_out, int out_size, void* d_ws, size_t ws_size,
                              hipStream_t stream) {
    const float* x  = (const float*)d_in[0];
    const float* W1 = (const float*)d_in[1];
    const float* b1 = (const float*)d_in[2];
    const float* wt = (const float*)d_in[3];
    const float* W2 = (const float*)d_in[4];
    const float* b2 = (const float*)d_in[5];
    (void)in_sizes; (void)n_in; (void)out_size; (void)d_ws; (void)ws_size;
    ode_kernel<<<Bn / 2, 64, 0, stream>>>(x, W1, b1, wt, W2, b2, (float*)d_out);
}